// Round 1
// 128.380 us; speedup vs baseline: 1.0138x; 1.0138x over previous
//
#include <hip/hip_runtime.h>

#define BB 32
#define NN_ 128
#define NIN 64
#define MH 256
#define MO 64
#define NH 256
#define NO 64
#define EDGES 16256

typedef _Float16 half8 __attribute__((ext_vector_type(8)));   // 8 f16 = 4 VGPRs
typedef _Float16 half2t __attribute__((ext_vector_type(2)));
typedef __attribute__((ext_vector_type(4))) float f32x4;      // MFMA acc

// ws layout (floats):
//   psb: [B][32][128][8] f16   off 0        = 524288 floats
//   prb: [B][N][256]     f16   off 524288   = 524288 floats
//   w2b: [32][64][8]     f16   off 1048576  = 8192 floats
//   agg: [B][N][MO]      fp32  off 1056768  = 262144 floats
//   o1b: [256][64]       f16   off 1318912  = 8192 floats
//   o2b: [256][256]      f16   off 1327104  = 32768 floats
//   o3b: [64][256]       f16   off 1359872  = 8192 floats

static __device__ __forceinline__ unsigned short f2h(float f) {
    return __builtin_bit_cast(unsigned short, (_Float16)f);   // v_cvt_f16_f32
}

// pack 8 fp32 -> 8 f16 via 4x v_cvt_pkrtz_f16_f32 (1 inst per pair)
static __device__ __forceinline__ half8 pack8h(float4 f0, float4 f1) {
    uint4 u;
    u.x = __builtin_bit_cast(unsigned, __builtin_amdgcn_cvt_pkrtz(f0.x, f0.y));
    u.y = __builtin_bit_cast(unsigned, __builtin_amdgcn_cvt_pkrtz(f0.z, f0.w));
    u.z = __builtin_bit_cast(unsigned, __builtin_amdgcn_cvt_pkrtz(f1.x, f1.y));
    u.w = __builtin_bit_cast(unsigned, __builtin_amdgcn_cvt_pkrtz(f1.z, f1.w));
    return __builtin_bit_cast(half8, u);
}

// relu(s + p) fully in packed-f16 domain: 4x v_pk_add_f16 + 4x v_pk_max_f16.
// Replaces the bf16 path's unpack(8) + add(8) + max(8) + pack(12) = 36 VALU
// with 8 VALU per fragment.
static __device__ __forceinline__ half8 addrelu(uint4 s, uint4 p) {
    half8 a = __builtin_bit_cast(half8, s) + __builtin_bit_cast(half8, p);
    half8 z = {};
    return __builtin_elementwise_max(a, z);
}

// ---------------------------------------------------------------------------
// Kernel 1: prep.
//   blocks 0..255   : fc1 partials via f16 MFMA. Block = 16 rows of x
//                     ([4096 x 64] @ W1^T halves -> ps, pr(+b1)), outputs
//                     stored f16 into psb [b][k/8][node][8] / prb [b][node][k].
//   blocks 256..319 : W2 -> f16 re-layout w2b[k/8][n][8]
//   blocks 320..703 : O1/O2/O3 -> f16 casts (already B-fragment layout)
// ---------------------------------------------------------------------------
__global__ __launch_bounds__(256) void prep_kernel(
    const float* __restrict__ x, const float* __restrict__ W1,
    const float* __restrict__ b1, const float* __restrict__ W2,
    const float* __restrict__ O1, const float* __restrict__ O2,
    const float* __restrict__ O3,
    unsigned short* __restrict__ psb, unsigned short* __restrict__ prb,
    unsigned short* __restrict__ w2b, unsigned short* __restrict__ o1b,
    unsigned short* __restrict__ o2b, unsigned short* __restrict__ o3b)
{
    int blk = blockIdx.x;
    int t = threadIdx.x;
    if (blk < 256) {
        int row0 = blk << 4;          // 16 consecutive global rows (b = blk>>3)
        int b = blk >> 3;
        int w = t >> 6, lane = t & 63, ml = lane & 15, q = lane >> 4;

        // A fragments: x rows row0..row0+15, K=64 over two MFMA k-steps
        half8 aX[2];
        #pragma unroll
        for (int s = 0; s < 2; ++s) {
            const float* base = x + (size_t)(row0 + ml) * NIN + s * 32 + q * 8;
            aX[s] = pack8h(*(const float4*)base, *(const float4*)(base + 4));
        }

        #pragma unroll
        for (int half = 0; half < 2; ++half) {     // 0 = sender(ps), 1 = recv(pr)
            #pragma unroll
            for (int nt = 0; nt < 4; ++nt) {
                int col = w * 64 + nt * 16 + ml;   // output unit h (0..255)
                const float* wrow = W1 + (size_t)col * (2 * NIN) + half * 64 + q * 8;
                f32x4 acc = (f32x4){0.f, 0.f, 0.f, 0.f};
                #pragma unroll
                for (int s = 0; s < 2; ++s) {
                    half8 bw = pack8h(*(const float4*)(wrow + 32 * s),
                                      *(const float4*)(wrow + 32 * s + 4));
                    acc = __builtin_amdgcn_mfma_f32_16x16x32_f16(aX[s], bw, acc, 0, 0, 0);
                }
                if (half == 0) {
                    #pragma unroll
                    for (int reg = 0; reg < 4; ++reg) {
                        int n = (row0 + q * 4 + reg) & 127;
                        psb[((size_t)(b * 32 + (col >> 3)) * NN_ + n) * 8 + (col & 7)]
                            = f2h(acc[reg]);
                    }
                } else {
                    float bv = b1[col];
                    #pragma unroll
                    for (int reg = 0; reg < 4; ++reg) {
                        int n = (row0 + q * 4 + reg) & 127;
                        prb[((size_t)(b * NN_) + n) * MH + col] = f2h(acc[reg] + bv);
                    }
                }
            }
        }
    } else if (blk < 320) {
        int i = ((blk - 256) << 8) + t;   // 0..16383
        int kc4 = i >> 9, rem = i & 511;
        int n = rem >> 3, k7 = i & 7;
        w2b[i] = f2h(W2[n * MH + kc4 * 8 + k7]);   // w2b[kc4][n][k7] = W2[n][k]
    } else {
        int i = ((blk - 320) << 8) + t;   // 0..98303
        if (i < 16384)       o1b[i]         = f2h(O1[i]);
        else if (i < 81920)  o2b[i - 16384] = f2h(O2[i - 16384]);
        else                 o3b[i - 81920] = f2h(O3[i - 81920]);
    }
}

// ---------------------------------------------------------------------------
// Kernel 2: edge fc2 as f16 MFMA + rtw-weighted segment sum.
// Block = (b, receiver pair r0,r1). DENSE sender mapping: slot = sender,
// self-edge masked via rtw=0 -> ps fragments shared across both receivers,
// w2 fragments amortized 2x. 4 waves; wave w owns slots [32w,32w+32)
// (2 M-tiles) x 4 N-tiles x 2 receivers = 16 MFMA per k-step.
// Inner loop now entirely packed-f16: addrelu is 8 VALU per A-fragment
// (was ~36 in the bf16 unpack/repack path).
// ---------------------------------------------------------------------------
__global__ __launch_bounds__(256, 3) void edge_kernel(
    const float* __restrict__ rt, const float* __restrict__ b2,
    const unsigned short* __restrict__ psb, const unsigned short* __restrict__ prb,
    const unsigned short* __restrict__ w2b, float* __restrict__ agg)
{
    int blk = blockIdx.x;
    int b = blk >> 6;
    int r0 = (blk & 63) << 1;
    int tid = threadIdx.x;
    int w = tid >> 6, lane = tid & 63, ml = lane & 15, q = lane >> 4;

    __shared__ float rtw_lds[2][128];
    __shared__ float red[2][4][64];
    {
        int rr = tid >> 7, s = tid & 127;
        int r = r0 + rr;
        float v = 0.f;
        if (s != r) {
            int e = r * 127 + s - (s > r ? 1 : 0);
            const float* p = rt + ((size_t)(b * EDGES + e)) * 2;
            v = p[0] + p[1];
        }
        rtw_lds[rr][s] = v;
    }
    __syncthreads();

    int slot0 = 32 * w + ml;
    int slot1 = slot0 + 16;

    const uint4* ps4 = (const uint4*)psb + (size_t)b * (32 * NN_);       // [kc4][node]
    const uint4* pr4_0 = (const uint4*)(prb + ((size_t)(b * NN_ + r0)) * MH);
    const uint4* pr4_1 = (const uint4*)(prb + ((size_t)(b * NN_ + r0 + 1)) * MH);
    const uint4* w24 = (const uint4*)w2b;                                // [kc4][n]

    f32x4 acc[2][2][4];   // [receiver][m-tile][n-tile]
    #pragma unroll
    for (int rr = 0; rr < 2; ++rr)
        #pragma unroll
        for (int mt = 0; mt < 2; ++mt)
            #pragma unroll
            for (int nt = 0; nt < 4; ++nt)
                acc[rr][mt][nt] = (f32x4){0.f, 0.f, 0.f, 0.f};

    #pragma unroll
    for (int kc = 0; kc < 8; ++kc) {
        int kc4 = 4 * kc + q;
        uint4 us0 = ps4[kc4 * NN_ + slot0];
        uint4 us1 = ps4[kc4 * NN_ + slot1];
        uint4 up0 = pr4_0[kc4];
        uint4 up1 = pr4_1[kc4];

        half8 a00 = addrelu(us0, up0);   // r0, m-tile 0
        half8 a01 = addrelu(us1, up0);   // r0, m-tile 1
        half8 a10 = addrelu(us0, up1);   // r1, m-tile 0
        half8 a11 = addrelu(us1, up1);   // r1, m-tile 1

        #pragma unroll
        for (int nt = 0; nt < 4; ++nt) {
            half8 bw = __builtin_bit_cast(half8, w24[kc4 * 64 + 16 * nt + ml]);
            acc[0][0][nt] = __builtin_amdgcn_mfma_f32_16x16x32_f16(a00, bw, acc[0][0][nt], 0, 0, 0);
            acc[0][1][nt] = __builtin_amdgcn_mfma_f32_16x16x32_f16(a01, bw, acc[0][1][nt], 0, 0, 0);
            acc[1][0][nt] = __builtin_amdgcn_mfma_f32_16x16x32_f16(a10, bw, acc[1][0][nt], 0, 0, 0);
            acc[1][1][nt] = __builtin_amdgcn_mfma_f32_16x16x32_f16(a11, bw, acc[1][1][nt], 0, 0, 0);
        }
    }

    float b2c[4];
    #pragma unroll
    for (int nt = 0; nt < 4; ++nt) b2c[nt] = b2[16 * nt + ml];

    #pragma unroll
    for (int rr = 0; rr < 2; ++rr) {
        float colsum[4] = {0.f, 0.f, 0.f, 0.f};
        #pragma unroll
        for (int mt = 0; mt < 2; ++mt) {
            int slotbase = 32 * w + 16 * mt + 4 * q;
            #pragma unroll
            for (int reg = 0; reg < 4; ++reg) {
                float rw = rtw_lds[rr][slotbase + reg];
                #pragma unroll
                for (int nt = 0; nt < 4; ++nt)
                    colsum[nt] += fmaxf(acc[rr][mt][nt][reg] + b2c[nt], 0.f) * rw;
            }
        }
        #pragma unroll
        for (int nt = 0; nt < 4; ++nt) {
            colsum[nt] += __shfl_xor(colsum[nt], 16);
            colsum[nt] += __shfl_xor(colsum[nt], 32);
        }
        if (lane < 16) {
            #pragma unroll
            for (int nt = 0; nt < 4; ++nt) red[rr][w][16 * nt + ml] = colsum[nt];
        }
    }
    __syncthreads();
    if (tid < 128) {
        int rr = tid >> 6, o = tid & 63;
        agg[((size_t)(b * NN_ + r0 + rr)) * MO + o] =
            red[rr][0][o] + red[rr][1][o] + red[rr][2][o] + red[rr][3][o];
    }
}

// ---------------------------------------------------------------------------
// Kernel 3: node MLP as 3 chained f16 MFMAs.
// ---------------------------------------------------------------------------
__global__ __launch_bounds__(256) void node_kernel(
    const float* __restrict__ agg,
    const unsigned short* __restrict__ O1b, const float* __restrict__ b1o,
    const unsigned short* __restrict__ O2b, const float* __restrict__ b2o,
    const unsigned short* __restrict__ O3b, const float* __restrict__ b3o,
    float* __restrict__ out)
{
    int tid = threadIdx.x;
    int w = tid >> 6, lane = tid & 63, ml = lane & 15, q = lane >> 4;
    int row0 = blockIdx.x << 4;

    __shared__ unsigned short h1L[16][264];
    __shared__ unsigned short h2L[16][264];

    half8 aA[2];
    #pragma unroll
    for (int s = 0; s < 2; ++s) {
        const float* base = agg + (size_t)(row0 + ml) * MO + 32 * s + q * 8;
        aA[s] = pack8h(*(const float4*)base, *(const float4*)(base + 4));
    }

    // fc1: [16 x 64] @ [64 x 256]
    #pragma unroll
    for (int nt = 0; nt < 4; ++nt) {
        int ntg = w * 4 + nt;
        f32x4 acc = (f32x4){0.f, 0.f, 0.f, 0.f};
        #pragma unroll
        for (int s = 0; s < 2; ++s) {
            half8 bw = *(const half8*)(O1b + (size_t)(ntg * 16 + ml) * 64 + 32 * s + q * 8);
            acc = __builtin_amdgcn_mfma_f32_16x16x32_f16(aA[s], bw, acc, 0, 0, 0);
        }
        float bv = b1o[ntg * 16 + ml];
        #pragma unroll
        for (int reg = 0; reg < 4; ++reg)
            h1L[q * 4 + reg][ntg * 16 + ml] = f2h(fmaxf(acc[reg] + bv, 0.f));
    }
    __syncthreads();

    // fc2: [16 x 256] @ [256 x 256]
    half8 aH[8];
    #pragma unroll
    for (int ks = 0; ks < 8; ++ks)
        aH[ks] = *(const half8*)&h1L[ml][32 * ks + q * 8];
    #pragma unroll
    for (int nt = 0; nt < 4; ++nt) {
        int ntg = w * 4 + nt;
        const unsigned short* wrow = O2b + (size_t)(ntg * 16 + ml) * NH + q * 8;
        f32x4 acc = (f32x4){0.f, 0.f, 0.f, 0.f};
        #pragma unroll
        for (int ks = 0; ks < 8; ++ks) {
            half8 bw = *(const half8*)(wrow + 32 * ks);
            acc = __builtin_amdgcn_mfma_f32_16x16x32_f16(aH[ks], bw, acc, 0, 0, 0);
        }
        float bv = b2o[ntg * 16 + ml];
        #pragma unroll
        for (int reg = 0; reg < 4; ++reg)
            h2L[q * 4 + reg][ntg * 16 + ml] = f2h(fmaxf(acc[reg] + bv, 0.f));
    }
    __syncthreads();

    // fc3: [16 x 256] @ [256 x 64]
    #pragma unroll
    for (int ks = 0; ks < 8; ++ks)
        aH[ks] = *(const half8*)&h2L[ml][32 * ks + q * 8];
    {
        const unsigned short* wrow = O3b + (size_t)(w * 16 + ml) * NH + q * 8;
        f32x4 acc = (f32x4){0.f, 0.f, 0.f, 0.f};
        #pragma unroll
        for (int ks = 0; ks < 8; ++ks) {
            half8 bw = *(const half8*)(wrow + 32 * ks);
            acc = __builtin_amdgcn_mfma_f32_16x16x32_f16(aH[ks], bw, acc, 0, 0, 0);
        }
        float bv = b3o[w * 16 + ml];
        #pragma unroll
        for (int reg = 0; reg < 4; ++reg)
            out[(size_t)(row0 + q * 4 + reg) * NO + w * 16 + ml] = acc[reg] + bv;
    }
}

// ---------------------------------------------------------------------------
extern "C" void kernel_launch(void* const* d_in, const int* in_sizes, int n_in,
                              void* d_out, int out_size, void* d_ws, size_t ws_size,
                              hipStream_t stream) {
    const float* x   = (const float*)d_in[0];
    const float* rt  = (const float*)d_in[3];
    const float* W1  = (const float*)d_in[4];
    const float* b1  = (const float*)d_in[5];
    const float* W2  = (const float*)d_in[6];
    const float* b2  = (const float*)d_in[7];
    const float* O1  = (const float*)d_in[8];
    const float* b1o = (const float*)d_in[9];
    const float* O2  = (const float*)d_in[10];
    const float* b2o = (const float*)d_in[11];
    const float* O3  = (const float*)d_in[12];
    const float* b3o = (const float*)d_in[13];

    float* ws  = (float*)d_ws;
    unsigned short* psb = (unsigned short*)ws;
    unsigned short* prb = (unsigned short*)(ws + 524288);
    unsigned short* w2b = (unsigned short*)(ws + 1048576);
    float* agg = ws + 1056768;
    unsigned short* o1b = (unsigned short*)(ws + 1318912);
    unsigned short* o2b = (unsigned short*)(ws + 1327104);
    unsigned short* o3b = (unsigned short*)(ws + 1359872);
    float* out = (float*)d_out;

    hipLaunchKernelGGL(prep_kernel, dim3(704), dim3(256), 0, stream,
                       x, W1, b1, W2, O1, O2, O3, psb, prb, w2b, o1b, o2b, o3b);
    hipLaunchKernelGGL(edge_kernel, dim3(2048), dim3(256), 0, stream,
                       rt, b2, psb, prb, w2b, agg);
    hipLaunchKernelGGL(node_kernel, dim3(256), dim3(256), 0, stream,
                       agg, o1b, b1o, o2b, b2o, o3b, b3o, out);
}